// Round 1
// baseline (673.239 us; speedup 1.0000x reference)
//
#include <hip/hip_runtime.h>

typedef __bf16 bf16x8 __attribute__((ext_vector_type(8)));
typedef __bf16 bf16x4 __attribute__((ext_vector_type(4)));
typedef float  f32x4  __attribute__((ext_vector_type(4)));

#define D_FEAT 128
#define BM 128
#define LDS_STRIDE 136   // 128 + 8 bf16 pad: keeps 16B alignment, rotates rows by 4 banks

__global__ void convert_weights_kernel(const float* __restrict__ W1,
                                       const float* __restrict__ W2,
                                       const float* __restrict__ W3,
                                       __bf16* __restrict__ wb) {
    int i = blockIdx.x * blockDim.x + threadIdx.x;   // 0..65535
    float v;
    if (i < 32768)      v = W1[i];
    else if (i < 49152) v = W2[i - 32768];
    else                v = W3[i - 49152];
    wb[i] = (__bf16)v;
}

__device__ __forceinline__ float lrelu(float x) {
    return x >= 0.0f ? x : 0.01f * x;
}

__launch_bounds__(256, 2)
__global__ void fused_mlp_kernel(const float* __restrict__ e,
                                 const float* __restrict__ h,
                                 const int*   __restrict__ src,
                                 const int*   __restrict__ dst,
                                 const __bf16* __restrict__ wb,   // W1b | W2b | W3b (bf16)
                                 const float* __restrict__ bias1,
                                 const float* __restrict__ bias2,
                                 const float* __restrict__ bias3,
                                 float* __restrict__ out,
                                 int E) {
    __shared__ __align__(16) __bf16 sX[BM][LDS_STRIDE];

    const int tid  = threadIdx.x;
    const int wave = tid >> 6;
    const int lane = tid & 63;
    const int l16  = lane & 15;
    const int quad = lane >> 4;
    const int row0 = blockIdx.x * BM;
    const int nb   = wave * 32;          // this wave's output-column base

    const __bf16* W1b = wb;              // [128][256]
    const __bf16* W2b = wb + 32768;      // [128][128]
    const __bf16* W3b = wb + 49152;      // [128][128]

    f32x4 acc[8][2];
    #pragma unroll
    for (int mi = 0; mi < 8; ++mi) {
        acc[mi][0] = (f32x4){0.f, 0.f, 0.f, 0.f};
        acc[mi][1] = (f32x4){0.f, 0.f, 0.f, 0.f};
    }

    // ---- stage e tile: 128 rows x 128 cols, f32 -> bf16 ----
    {
        const int r0 = tid >> 5;          // 0..7
        const int c4 = (tid & 31) * 4;    // float col, step 4
        #pragma unroll 4
        for (int it = 0; it < 16; ++it) {
            const int row = it * 8 + r0;
            int rg = row0 + row; if (rg >= E) rg = E - 1;
            float4 v = *reinterpret_cast<const float4*>(e + (size_t)rg * D_FEAT + c4);
            bf16x4 b;
            b[0] = (__bf16)v.x; b[1] = (__bf16)v.y;
            b[2] = (__bf16)v.z; b[3] = (__bf16)v.w;
            *reinterpret_cast<bf16x4*>(&sX[row][c4]) = b;
        }
    }
    __syncthreads();

    // ---- layer 1, first K-half (e part, W1 cols 0..127) ----
    #pragma unroll
    for (int ks = 0; ks < 4; ++ks) {
        const int kofs = ks * 32 + quad * 8;
        bf16x8 w0 = *reinterpret_cast<const bf16x8*>(W1b + (size_t)(nb + l16) * 256 + kofs);
        bf16x8 w1 = *reinterpret_cast<const bf16x8*>(W1b + (size_t)(nb + 16 + l16) * 256 + kofs);
        #pragma unroll
        for (int mi = 0; mi < 8; ++mi) {
            bf16x8 a = *reinterpret_cast<const bf16x8*>(&sX[mi * 16 + l16][kofs]);
            acc[mi][0] = __builtin_amdgcn_mfma_f32_16x16x32_bf16(a, w0, acc[mi][0], 0, 0, 0);
            acc[mi][1] = __builtin_amdgcn_mfma_f32_16x16x32_bf16(a, w1, acc[mi][1], 0, 0, 0);
        }
    }
    __syncthreads();

    // ---- stage hs tile: h[src]+h[dst], f32 -> bf16 ----
    {
        const int rg16 = tid >> 4;          // 0..15
        const int c8   = (tid & 15) * 8;    // float col, step 8
        #pragma unroll 2
        for (int it = 0; it < 8; ++it) {
            const int row = it * 16 + rg16;
            int rg = row0 + row; if (rg >= E) rg = E - 1;
            const int s  = src[rg];
            const int d2 = dst[rg];
            const float4* hs = reinterpret_cast<const float4*>(h + (size_t)s  * D_FEAT + c8);
            const float4* hd = reinterpret_cast<const float4*>(h + (size_t)d2 * D_FEAT + c8);
            float4 a0 = hs[0], a1 = hs[1];
            float4 d0 = hd[0], d1 = hd[1];
            bf16x8 b;
            b[0] = (__bf16)(a0.x + d0.x); b[1] = (__bf16)(a0.y + d0.y);
            b[2] = (__bf16)(a0.z + d0.z); b[3] = (__bf16)(a0.w + d0.w);
            b[4] = (__bf16)(a1.x + d1.x); b[5] = (__bf16)(a1.y + d1.y);
            b[6] = (__bf16)(a1.z + d1.z); b[7] = (__bf16)(a1.w + d1.w);
            *reinterpret_cast<bf16x8*>(&sX[row][c8]) = b;
        }
    }
    __syncthreads();

    // ---- layer 1, second K-half (hs part, W1 cols 128..255) ----
    #pragma unroll
    for (int ks = 0; ks < 4; ++ks) {
        const int kofs = ks * 32 + quad * 8;
        bf16x8 w0 = *reinterpret_cast<const bf16x8*>(W1b + (size_t)(nb + l16) * 256 + 128 + kofs);
        bf16x8 w1 = *reinterpret_cast<const bf16x8*>(W1b + (size_t)(nb + 16 + l16) * 256 + 128 + kofs);
        #pragma unroll
        for (int mi = 0; mi < 8; ++mi) {
            bf16x8 a = *reinterpret_cast<const bf16x8*>(&sX[mi * 16 + l16][kofs]);
            acc[mi][0] = __builtin_amdgcn_mfma_f32_16x16x32_bf16(a, w0, acc[mi][0], 0, 0, 0);
            acc[mi][1] = __builtin_amdgcn_mfma_f32_16x16x32_bf16(a, w1, acc[mi][1], 0, 0, 0);
        }
    }

    // ---- layer 1 epilogue: bias + lrelu -> bf16 act back into sX ----
    {
        const float bA = bias1[nb + l16];
        const float bB = bias1[nb + 16 + l16];
        __syncthreads();   // everyone done reading sX
        #pragma unroll
        for (int mi = 0; mi < 8; ++mi) {
            #pragma unroll
            for (int nt = 0; nt < 2; ++nt) {
                #pragma unroll
                for (int r = 0; r < 4; ++r) {
                    const int row = mi * 16 + quad * 4 + r;
                    const int col = nb + nt * 16 + l16;
                    float v = lrelu(acc[mi][nt][r] + (nt ? bB : bA));
                    sX[row][col] = (__bf16)v;
                    acc[mi][nt][r] = 0.0f;
                }
            }
        }
    }
    __syncthreads();

    // ---- layer 2 ----
    #pragma unroll
    for (int ks = 0; ks < 4; ++ks) {
        const int kofs = ks * 32 + quad * 8;
        bf16x8 w0 = *reinterpret_cast<const bf16x8*>(W2b + (size_t)(nb + l16) * 128 + kofs);
        bf16x8 w1 = *reinterpret_cast<const bf16x8*>(W2b + (size_t)(nb + 16 + l16) * 128 + kofs);
        #pragma unroll
        for (int mi = 0; mi < 8; ++mi) {
            bf16x8 a = *reinterpret_cast<const bf16x8*>(&sX[mi * 16 + l16][kofs]);
            acc[mi][0] = __builtin_amdgcn_mfma_f32_16x16x32_bf16(a, w0, acc[mi][0], 0, 0, 0);
            acc[mi][1] = __builtin_amdgcn_mfma_f32_16x16x32_bf16(a, w1, acc[mi][1], 0, 0, 0);
        }
    }

    // ---- layer 2 epilogue ----
    {
        const float bA = bias2[nb + l16];
        const float bB = bias2[nb + 16 + l16];
        __syncthreads();
        #pragma unroll
        for (int mi = 0; mi < 8; ++mi) {
            #pragma unroll
            for (int nt = 0; nt < 2; ++nt) {
                #pragma unroll
                for (int r = 0; r < 4; ++r) {
                    const int row = mi * 16 + quad * 4 + r;
                    const int col = nb + nt * 16 + l16;
                    float v = lrelu(acc[mi][nt][r] + (nt ? bB : bA));
                    sX[row][col] = (__bf16)v;
                    acc[mi][nt][r] = 0.0f;
                }
            }
        }
    }
    __syncthreads();

    // ---- layer 3 ----
    #pragma unroll
    for (int ks = 0; ks < 4; ++ks) {
        const int kofs = ks * 32 + quad * 8;
        bf16x8 w0 = *reinterpret_cast<const bf16x8*>(W3b + (size_t)(nb + l16) * 128 + kofs);
        bf16x8 w1 = *reinterpret_cast<const bf16x8*>(W3b + (size_t)(nb + 16 + l16) * 128 + kofs);
        #pragma unroll
        for (int mi = 0; mi < 8; ++mi) {
            bf16x8 a = *reinterpret_cast<const bf16x8*>(&sX[mi * 16 + l16][kofs]);
            acc[mi][0] = __builtin_amdgcn_mfma_f32_16x16x32_bf16(a, w0, acc[mi][0], 0, 0, 0);
            acc[mi][1] = __builtin_amdgcn_mfma_f32_16x16x32_bf16(a, w1, acc[mi][1], 0, 0, 0);
        }
    }

    // ---- layer 3 epilogue: bias + lrelu -> f32 global out ----
    {
        const float bA = bias3[nb + l16];
        const float bB = bias3[nb + 16 + l16];
        #pragma unroll
        for (int mi = 0; mi < 8; ++mi) {
            #pragma unroll
            for (int nt = 0; nt < 2; ++nt) {
                #pragma unroll
                for (int r = 0; r < 4; ++r) {
                    const int row = mi * 16 + quad * 4 + r;
                    const int col = nb + nt * 16 + l16;
                    const int rg = row0 + row;
                    if (rg < E) {
                        out[(size_t)rg * D_FEAT + col] = lrelu(acc[mi][nt][r] + (nt ? bB : bA));
                    }
                }
            }
        }
    }
}

extern "C" void kernel_launch(void* const* d_in, const int* in_sizes, int n_in,
                              void* d_out, int out_size, void* d_ws, size_t ws_size,
                              hipStream_t stream) {
    const float* e   = (const float*)d_in[0];
    const float* h   = (const float*)d_in[1];
    const int*   src = (const int*)d_in[2];
    const int*   dst = (const int*)d_in[3];
    const float* W1  = (const float*)d_in[4];
    const float* b1  = (const float*)d_in[5];
    const float* W2  = (const float*)d_in[6];
    const float* b2  = (const float*)d_in[7];
    const float* W3  = (const float*)d_in[8];
    const float* b3  = (const float*)d_in[9];
    float* out = (float*)d_out;
    __bf16* wb = (__bf16*)d_ws;   // needs 65536 bf16 = 128 KiB of scratch

    const int E = in_sizes[2];            // 640000
    const int nblocks = (E + BM - 1) / BM;

    convert_weights_kernel<<<256, 256, 0, stream>>>(W1, W2, W3, wb);
    fused_mlp_kernel<<<nblocks, 256, 0, stream>>>(e, h, src, dst, wb, b1, b2, b3, out, E);
}